// Round 1
// baseline (995.934 us; speedup 1.0000x reference)
//
#include <hip/hip_runtime.h>
#include <math.h>

// ---------------- problem constants (checked against in_sizes at launch) ---
#define DIN   32
#define F1    64   // H1*C1
#define F2    64   // H2*C2

// ---------------- CSR build ------------------------------------------------

__global__ void count_kernel(const int* __restrict__ dstr, const float* __restrict__ ea,
                             int* __restrict__ cnt, float* __restrict__ sums, int E) {
    int e = blockIdx.x * blockDim.x + threadIdx.x;
    if (e >= E) return;
    int d = dstr[e];
    atomicAdd(&cnt[d], 1);
    atomicAdd(&sums[d * 2 + 0], ea[e * 2 + 0]);
    atomicAdd(&sums[d * 2 + 1], ea[e * 2 + 1]);
}

// block-wise exclusive scan of cnt (256/block), emits per-elem exclusive partial + block totals
__global__ void scan_blocks(const int* __restrict__ cnt, int* __restrict__ partial,
                            int* __restrict__ btot, int n) {
    __shared__ int sh[256];
    int t = threadIdx.x;
    int i = blockIdx.x * 256 + t;
    int v = (i < n) ? cnt[i] : 0;
    sh[t] = v; __syncthreads();
    for (int off = 1; off < 256; off <<= 1) {
        int x = (t >= off) ? sh[t - off] : 0;
        __syncthreads();
        sh[t] += x;
        __syncthreads();
    }
    if (i < n) partial[i] = sh[t] - v;        // exclusive within block
    if (t == 255) btot[blockIdx.x] = sh[t];   // block total
}

// scan the (<256) block totals in-place -> exclusive block offsets
__global__ void scan_top(int* __restrict__ btot, int nb) {
    __shared__ int sh[256];
    int t = threadIdx.x;
    int v = (t < nb) ? btot[t] : 0;
    sh[t] = v; __syncthreads();
    for (int off = 1; off < 256; off <<= 1) {
        int x = (t >= off) ? sh[t - off] : 0;
        __syncthreads();
        sh[t] += x;
        __syncthreads();
    }
    if (t < nb) btot[t] = sh[t] - v;
}

// finalize row_ptr / cur copy / loop_attr (self-loop edge attr = mean of incoming)
__global__ void scan_add(const int* __restrict__ partial, const int* __restrict__ boff,
                         const int* __restrict__ cnt, const float* __restrict__ sums,
                         int* __restrict__ row_ptr, int* __restrict__ cur,
                         float* __restrict__ loop_attr, int n, int E) {
    int i = blockIdx.x * blockDim.x + threadIdx.x;
    if (i > n) return;
    if (i == n) { row_ptr[n] = E; return; }
    int r = partial[i] + boff[i >> 8];
    row_ptr[i] = r;
    cur[i] = r;
    float c = fmaxf((float)cnt[i], 1.0f);
    loop_attr[i * 2 + 0] = sums[i * 2 + 0] / c;
    loop_attr[i * 2 + 1] = sums[i * 2 + 1] / c;
}

__global__ void scatter_kernel(const int* __restrict__ srcr, const int* __restrict__ dstr,
                               const float* __restrict__ ea, int* __restrict__ cur,
                               int* __restrict__ ssrc, float* __restrict__ sea, int E) {
    int e = blockIdx.x * blockDim.x + threadIdx.x;
    if (e >= E) return;
    int d = dstr[e];
    int p = atomicAdd(&cur[d], 1);
    ssrc[p] = srcr[e];
    sea[p * 2 + 0] = ea[e * 2 + 0];
    sea[p * 2 + 1] = ea[e * 2 + 1];
}

// ---------------- dense linear: xl = x@Wl+bl, xr = x@Wr+br -----------------
// block = 256 threads, 2 nodes/block; 128 out features per node (64 l + 64 r)
template <int K>
__global__ void lin_lr_kernel(const float* __restrict__ x,
                              const float* __restrict__ Wl, const float* __restrict__ bl,
                              const float* __restrict__ Wr, const float* __restrict__ br,
                              float* __restrict__ xl, float* __restrict__ xr, int n) {
    __shared__ float Wsh[K][128];
    __shared__ float bsh[128];
    int t = threadIdx.x;
    for (int idx = t; idx < K * 128; idx += 256) {
        int k = idx >> 7, j = idx & 127;
        Wsh[k][j] = (j < 64) ? Wl[k * 64 + j] : Wr[k * 64 + (j - 64)];
    }
    if (t < 128) bsh[t] = (t < 64) ? bl[t] : br[t - 64];
    __syncthreads();
    int nl = t >> 7;        // 0..1 (node within block)
    int j  = t & 127;       // output feature (0..63 -> l, 64..127 -> r)
    int node = blockIdx.x * 2 + nl;
    if (node >= n) return;
    const float* xrow = x + node * K;
    float acc = bsh[j];
#pragma unroll
    for (int k = 0; k < K; k++) acc += xrow[k] * Wsh[k][j];
    if (j < 64) xl[node * 64 + j] = acc;
    else        xr[node * 64 + (j - 64)] = acc;
}

// ---------------- GATv2 edge phase: one wave per dst node, online softmax --
// lane = h*C + c; logits reduced over the C-lane group via shfl_xor.
template <int H, int C>
__global__ void gat_kernel(const float* __restrict__ xl, const float* __restrict__ xr,
                           const int* __restrict__ row_ptr, const int* __restrict__ ssrc,
                           const float* __restrict__ sea, const float* __restrict__ loop_attr,
                           const float* __restrict__ We, const float* __restrict__ att,
                           const float* __restrict__ bias, float* __restrict__ out, int n) {
    const int F = H * C;
    int lane = threadIdx.x & 63;
    int wid = (blockIdx.x * blockDim.x + threadIdx.x) >> 6;
    if (wid >= n) return;
    int i = wid;

    float xri = xr[i * F + lane];
    float we0 = We[lane], we1 = We[F + lane];
    float a = att[lane];

    // self-loop first (guarantees denom>0, avoids -inf init)
    float la0 = loop_attr[i * 2 + 0], la1 = loop_attr[i * 2 + 1];
    float xlv = xl[i * F + lane];
    float z = xlv + xri + la0 * we0 + la1 * we1;
    z = (z > 0.f) ? z : 0.2f * z;
    float l0 = z * a;
#pragma unroll
    for (int m = 1; m < C; m <<= 1) l0 += __shfl_xor(l0, m, 64);
    float mx = l0;       // running max logit (uniform within C-group)
    float den = 1.0f;    // exp(l0 - mx) = 1
    float acc = xlv;     // 1 * xlv

    int e0 = row_ptr[i], e1 = row_ptr[i + 1];
    for (int e = e0; e < e1; e++) {
        int s = ssrc[e];
        float2 eav = ((const float2*)sea)[e];
        float xv = xl[s * F + lane];
        float zz = xv + xri + eav.x * we0 + eav.y * we1;
        zz = (zz > 0.f) ? zz : 0.2f * zz;
        float l = zz * a;
#pragma unroll
        for (int m = 1; m < C; m <<= 1) l += __shfl_xor(l, m, 64);
        float nm = fmaxf(mx, l);
        float sc = __expf(mx - nm);
        float p  = __expf(l - nm);
        den = den * sc + p;
        acc = acc * sc + p * xv;
        mx = nm;
    }
    float o = acc / den + bias[lane];
    out[i * F + lane] = fmaxf(o, 0.f);   // ReLU after each layer
}

// ---------------- heads: actor(tanh) + critic + std ------------------------
__global__ void heads_kernel(const float* __restrict__ h, const float* __restrict__ wa,
                             const float* __restrict__ ba, const float* __restrict__ wc,
                             const float* __restrict__ bc, const float* __restrict__ ls,
                             float* __restrict__ out, int n) {
    if (blockIdx.x == 0 && threadIdx.x < 2)
        out[(size_t)n * 2 + threadIdx.x] = expf(ls[threadIdx.x]);
    int lane = threadIdx.x & 63;
    int wid = (blockIdx.x * blockDim.x + threadIdx.x) >> 6;
    if (wid >= n) return;
    float hv = h[wid * 64 + lane];
    float d0 = hv * wa[lane * 2 + 0];
    float d1 = hv * wa[lane * 2 + 1];
    float d2 = hv * wc[lane];
#pragma unroll
    for (int m = 1; m < 64; m <<= 1) {
        d0 += __shfl_xor(d0, m, 64);
        d1 += __shfl_xor(d1, m, 64);
        d2 += __shfl_xor(d2, m, 64);
    }
    if (lane == 0) {
        out[wid * 2 + 0] = tanhf(d0 + ba[0]);
        out[wid * 2 + 1] = tanhf(d1 + ba[1]);
        out[(size_t)n * 2 + 2 + wid] = d2 + bc[0];
    }
}

// ---------------- launch ---------------------------------------------------

extern "C" void kernel_launch(void* const* d_in, const int* in_sizes, int n_in,
                              void* d_out, int out_size, void* d_ws, size_t ws_size,
                              hipStream_t stream) {
    const float* x    = (const float*)d_in[0];
    const int*   ei   = (const int*)  d_in[1];
    const float* ea   = (const float*)d_in[2];
    const float* w1l  = (const float*)d_in[3];
    const float* b1l  = (const float*)d_in[4];
    const float* w1r  = (const float*)d_in[5];
    const float* b1r  = (const float*)d_in[6];
    const float* w1e  = (const float*)d_in[7];
    const float* att1 = (const float*)d_in[8];
    const float* bias1= (const float*)d_in[9];
    const float* w2l  = (const float*)d_in[10];
    const float* b2l  = (const float*)d_in[11];
    const float* w2r  = (const float*)d_in[12];
    const float* b2r  = (const float*)d_in[13];
    const float* w2e  = (const float*)d_in[14];
    const float* att2 = (const float*)d_in[15];
    const float* bias2= (const float*)d_in[16];
    const float* wa   = (const float*)d_in[17];
    const float* ba   = (const float*)d_in[18];
    const float* wc   = (const float*)d_in[19];
    const float* bc   = (const float*)d_in[20];
    const float* ls   = (const float*)d_in[21];

    const int N = in_sizes[0] / DIN;
    const int E = in_sizes[2] / 2;
    const int* srcr = ei;       // edge_index[0,:]
    const int* dstr = ei + E;   // edge_index[1,:]

    // workspace carve (256B aligned)
    char* p = (char*)d_ws;
    auto alloc = [&](size_t bytes) -> void* {
        void* r = (void*)p;
        p += (bytes + 255) & ~(size_t)255;
        return r;
    };
    int*   cnt     = (int*)  alloc((size_t)N * 4);
    float* sums    = (float*)alloc((size_t)N * 8);
    int*   partial = (int*)  alloc((size_t)N * 4);
    int*   btot    = (int*)  alloc(256 * 4);
    int*   row_ptr = (int*)  alloc((size_t)(N + 1) * 4);
    int*   cur     = (int*)  alloc((size_t)N * 4);
    float* loopat  = (float*)alloc((size_t)N * 8);
    int*   ssrc    = (int*)  alloc((size_t)E * 4);
    float* sea     = (float*)alloc((size_t)E * 8);
    float* xl      = (float*)alloc((size_t)N * F1 * 4);
    float* xr      = (float*)alloc((size_t)N * F1 * 4);
    float* h1      = (float*)alloc((size_t)N * F1 * 4);
    float* h2      = (float*)alloc((size_t)N * F2 * 4);
    (void)ws_size; (void)n_in; (void)out_size;

    // zero the accumulators (cnt, sums)
    hipMemsetAsync(cnt, 0, (size_t)N * 4, stream);
    hipMemsetAsync(sums, 0, (size_t)N * 8, stream);

    const int TB = 256;
    int gridE  = (E + TB - 1) / TB;
    int nbScan = (N + TB - 1) / TB;          // <= 256 required (196 for N=50000)
    int gridN1 = (N + 1 + TB - 1) / TB;
    int gridLin = (N + 1) / 2;
    int gridWave = (N + 3) / 4;              // 4 waves (nodes) per 256-thread block

    // CSR build + self-loop attrs
    count_kernel<<<gridE, TB, 0, stream>>>(dstr, ea, cnt, sums, E);
    scan_blocks<<<nbScan, TB, 0, stream>>>(cnt, partial, btot, N);
    scan_top<<<1, TB, 0, stream>>>(btot, nbScan);
    scan_add<<<gridN1, TB, 0, stream>>>(partial, btot, cnt, sums, row_ptr, cur, loopat, N, E);
    scatter_kernel<<<gridE, TB, 0, stream>>>(srcr, dstr, ea, cur, ssrc, sea, E);

    // layer 1
    lin_lr_kernel<DIN><<<gridLin, TB, 0, stream>>>(x, w1l, b1l, w1r, b1r, xl, xr, N);
    gat_kernel<4, 16><<<gridWave, TB, 0, stream>>>(xl, xr, row_ptr, ssrc, sea, loopat,
                                                   w1e, att1, bias1, h1, N);
    // layer 2
    lin_lr_kernel<F1><<<gridLin, TB, 0, stream>>>(h1, w2l, b2l, w2r, b2r, xl, xr, N);
    gat_kernel<2, 32><<<gridWave, TB, 0, stream>>>(xl, xr, row_ptr, ssrc, sea, loopat,
                                                   w2e, att2, bias2, h2, N);
    // heads
    heads_kernel<<<gridWave, TB, 0, stream>>>(h2, wa, ba, wc, bc, ls, (float*)d_out, N);
}

// Round 2
// 759.028 us; speedup vs baseline: 1.3121x; 1.3121x over previous
//
#include <hip/hip_runtime.h>
#include <math.h>

#define DIN   32
#define F1    64   // H1*C1
#define F2    64   // H2*C2

// ---------------- CSR build (rank trick: count atomic also yields placement) ---

__global__ void count_rank_kernel(const int* __restrict__ dstr, int* __restrict__ cnt,
                                  int* __restrict__ rank, int E) {
    int e = blockIdx.x * blockDim.x + threadIdx.x;
    if (e >= E) return;
    int d = dstr[e];
    rank[e] = atomicAdd(&cnt[d], 1);   // rank write is coalesced (indexed by e)
}

// block-wise exclusive scan of cnt (256/block)
__global__ void scan_blocks(const int* __restrict__ cnt, int* __restrict__ partial,
                            int* __restrict__ btot, int n) {
    __shared__ int sh[256];
    int t = threadIdx.x;
    int i = blockIdx.x * 256 + t;
    int v = (i < n) ? cnt[i] : 0;
    sh[t] = v; __syncthreads();
    for (int off = 1; off < 256; off <<= 1) {
        int x = (t >= off) ? sh[t - off] : 0;
        __syncthreads();
        sh[t] += x;
        __syncthreads();
    }
    if (i < n) partial[i] = sh[t] - v;
    if (t == 255) btot[blockIdx.x] = sh[t];
}

__global__ void scan_top(int* __restrict__ btot, int nb) {
    __shared__ int sh[256];
    int t = threadIdx.x;
    int v = (t < nb) ? btot[t] : 0;
    sh[t] = v; __syncthreads();
    for (int off = 1; off < 256; off <<= 1) {
        int x = (t >= off) ? sh[t - off] : 0;
        __syncthreads();
        sh[t] += x;
        __syncthreads();
    }
    if (t < nb) btot[t] = sh[t] - v;
}

__global__ void scan_add(const int* __restrict__ partial, const int* __restrict__ boff,
                         int* __restrict__ row_ptr, int n, int E) {
    int i = blockIdx.x * blockDim.x + threadIdx.x;
    if (i > n) return;
    row_ptr[i] = (i == n) ? E : (partial[i] + boff[i >> 8]);
}

// scatter edges into CSR order — NO atomics (pos = row_ptr[d] + rank[e])
__global__ void scatter_kernel(const int* __restrict__ srcr, const int* __restrict__ dstr,
                               const int* __restrict__ rank, const int* __restrict__ row_ptr,
                               const float* __restrict__ ea,
                               int* __restrict__ ssrc, float* __restrict__ sea, int E) {
    int e = blockIdx.x * blockDim.x + threadIdx.x;
    if (e >= E) return;
    int pos = row_ptr[dstr[e]] + rank[e];
    ssrc[pos] = srcr[e];
    ((float2*)sea)[pos] = ((const float2*)ea)[e];
}

// ---------------- dense linear: xl = x@Wl+bl, xr = x@Wr+br -----------------
template <int K>
__global__ void lin_lr_kernel(const float* __restrict__ x,
                              const float* __restrict__ Wl, const float* __restrict__ bl,
                              const float* __restrict__ Wr, const float* __restrict__ br,
                              float* __restrict__ xl, float* __restrict__ xr, int n) {
    __shared__ float Wsh[K][128];
    __shared__ float bsh[128];
    int t = threadIdx.x;
    for (int idx = t; idx < K * 128; idx += 256) {
        int k = idx >> 7, j = idx & 127;
        Wsh[k][j] = (j < 64) ? Wl[k * 64 + j] : Wr[k * 64 + (j - 64)];
    }
    if (t < 128) bsh[t] = (t < 64) ? bl[t] : br[t - 64];
    __syncthreads();
    int nl = t >> 7;
    int j  = t & 127;
    int node = blockIdx.x * 2 + nl;
    if (node >= n) return;
    const float* xrow = x + node * K;
    float acc = bsh[j];
#pragma unroll
    for (int k = 0; k < K; k++) acc += xrow[k] * Wsh[k][j];
    if (j < 64) xl[node * 64 + j] = acc;
    else        xr[node * 64 + (j - 64)] = acc;
}

// ---------------- GATv2 edge phase: one wave per dst node, online softmax --
// Self-loop (attr = mean of incoming edge attrs) is folded in LAST; the mean
// is accumulated inline from the same eav loads the edge loop already does.
template <int H, int C>
__global__ void gat_kernel(const float* __restrict__ xl, const float* __restrict__ xr,
                           const int* __restrict__ row_ptr, const int* __restrict__ ssrc,
                           const float* __restrict__ sea,
                           const float* __restrict__ We, const float* __restrict__ att,
                           const float* __restrict__ bias, float* __restrict__ out, int n) {
    const int F = H * C;
    int lane = threadIdx.x & 63;
    int wid = (blockIdx.x * blockDim.x + threadIdx.x) >> 6;
    if (wid >= n) return;
    int i = wid;

    float xri = xr[i * F + lane];
    float we0 = We[lane], we1 = We[F + lane];
    float a = att[lane];

    float mx = -INFINITY, den = 0.f, acc = 0.f;
    float s0 = 0.f, s1 = 0.f;   // running sum of edge attrs (same on all lanes)

    int e0 = row_ptr[i], e1 = row_ptr[i + 1];
    for (int e = e0; e < e1; e++) {
        int s = ssrc[e];
        float2 eav = ((const float2*)sea)[e];
        s0 += eav.x; s1 += eav.y;
        float xv = xl[s * F + lane];
        float zz = xv + xri + eav.x * we0 + eav.y * we1;
        zz = (zz > 0.f) ? zz : 0.2f * zz;
        float l = zz * a;
#pragma unroll
        for (int m = 1; m < C; m <<= 1) l += __shfl_xor(l, m, 64);
        float nm = fmaxf(mx, l);
        float sc = __expf(mx - nm);
        float p  = __expf(l - nm);
        den = den * sc + p;
        acc = acc * sc + p * xv;
        mx = nm;
    }
    // self-loop: attr = mean of incoming (or 0-div-guard when deg==0)
    float degc = fmaxf((float)(e1 - e0), 1.0f);
    float la0 = s0 / degc, la1 = s1 / degc;
    float xlv = xl[i * F + lane];
    float z = xlv + xri + la0 * we0 + la1 * we1;
    z = (z > 0.f) ? z : 0.2f * z;
    float l = z * a;
#pragma unroll
    for (int m = 1; m < C; m <<= 1) l += __shfl_xor(l, m, 64);
    float nm = fmaxf(mx, l);
    float sc = __expf(mx - nm);
    float p  = __expf(l - nm);
    den = den * sc + p;
    acc = acc * sc + p * xlv;

    float o = acc / den + bias[lane];
    out[i * F + lane] = fmaxf(o, 0.f);   // ReLU after each layer
}

// ---------------- heads: actor(tanh) + critic + std ------------------------
__global__ void heads_kernel(const float* __restrict__ h, const float* __restrict__ wa,
                             const float* __restrict__ ba, const float* __restrict__ wc,
                             const float* __restrict__ bc, const float* __restrict__ ls,
                             float* __restrict__ out, int n) {
    if (blockIdx.x == 0 && threadIdx.x < 2)
        out[(size_t)n * 2 + threadIdx.x] = expf(ls[threadIdx.x]);
    int lane = threadIdx.x & 63;
    int wid = (blockIdx.x * blockDim.x + threadIdx.x) >> 6;
    if (wid >= n) return;
    float hv = h[wid * 64 + lane];
    float d0 = hv * wa[lane * 2 + 0];
    float d1 = hv * wa[lane * 2 + 1];
    float d2 = hv * wc[lane];
#pragma unroll
    for (int m = 1; m < 64; m <<= 1) {
        d0 += __shfl_xor(d0, m, 64);
        d1 += __shfl_xor(d1, m, 64);
        d2 += __shfl_xor(d2, m, 64);
    }
    if (lane == 0) {
        out[wid * 2 + 0] = tanhf(d0 + ba[0]);
        out[wid * 2 + 1] = tanhf(d1 + ba[1]);
        out[(size_t)n * 2 + 2 + wid] = d2 + bc[0];
    }
}

// ---------------- launch ---------------------------------------------------

extern "C" void kernel_launch(void* const* d_in, const int* in_sizes, int n_in,
                              void* d_out, int out_size, void* d_ws, size_t ws_size,
                              hipStream_t stream) {
    const float* x    = (const float*)d_in[0];
    const int*   ei   = (const int*)  d_in[1];
    const float* ea   = (const float*)d_in[2];
    const float* w1l  = (const float*)d_in[3];
    const float* b1l  = (const float*)d_in[4];
    const float* w1r  = (const float*)d_in[5];
    const float* b1r  = (const float*)d_in[6];
    const float* w1e  = (const float*)d_in[7];
    const float* att1 = (const float*)d_in[8];
    const float* bias1= (const float*)d_in[9];
    const float* w2l  = (const float*)d_in[10];
    const float* b2l  = (const float*)d_in[11];
    const float* w2r  = (const float*)d_in[12];
    const float* b2r  = (const float*)d_in[13];
    const float* w2e  = (const float*)d_in[14];
    const float* att2 = (const float*)d_in[15];
    const float* bias2= (const float*)d_in[16];
    const float* wa   = (const float*)d_in[17];
    const float* ba   = (const float*)d_in[18];
    const float* wc   = (const float*)d_in[19];
    const float* bc   = (const float*)d_in[20];
    const float* ls   = (const float*)d_in[21];

    const int N = in_sizes[0] / DIN;
    const int E = in_sizes[2] / 2;
    const int* srcr = ei;
    const int* dstr = ei + E;

    char* p = (char*)d_ws;
    auto alloc = [&](size_t bytes) -> void* {
        void* r = (void*)p;
        p += (bytes + 255) & ~(size_t)255;
        return r;
    };
    int*   cnt     = (int*)  alloc((size_t)N * 4);
    int*   rank    = (int*)  alloc((size_t)E * 4);
    int*   partial = (int*)  alloc((size_t)N * 4);
    int*   btot    = (int*)  alloc(256 * 4);
    int*   row_ptr = (int*)  alloc((size_t)(N + 1) * 4);
    int*   ssrc    = (int*)  alloc((size_t)E * 4);
    float* sea     = (float*)alloc((size_t)E * 8);
    float* xl      = (float*)alloc((size_t)N * F1 * 4);
    float* xr      = (float*)alloc((size_t)N * F1 * 4);
    float* h1      = (float*)alloc((size_t)N * F1 * 4);
    float* h2      = (float*)alloc((size_t)N * F2 * 4);
    (void)ws_size; (void)n_in; (void)out_size;

    hipMemsetAsync(cnt, 0, (size_t)N * 4, stream);

    const int TB = 256;
    int gridE  = (E + TB - 1) / TB;
    int nbScan = (N + TB - 1) / TB;          // <= 256 required (196 for N=50000)
    int gridN1 = (N + 1 + TB - 1) / TB;
    int gridLin = (N + 1) / 2;
    int gridWave = (N + 3) / 4;

    count_rank_kernel<<<gridE, TB, 0, stream>>>(dstr, cnt, rank, E);
    scan_blocks<<<nbScan, TB, 0, stream>>>(cnt, partial, btot, N);
    scan_top<<<1, TB, 0, stream>>>(btot, nbScan);
    scan_add<<<gridN1, TB, 0, stream>>>(partial, btot, row_ptr, N, E);
    scatter_kernel<<<gridE, TB, 0, stream>>>(srcr, dstr, rank, row_ptr, ea, ssrc, sea, E);

    lin_lr_kernel<DIN><<<gridLin, TB, 0, stream>>>(x, w1l, b1l, w1r, b1r, xl, xr, N);
    gat_kernel<4, 16><<<gridWave, TB, 0, stream>>>(xl, xr, row_ptr, ssrc, sea,
                                                   w1e, att1, bias1, h1, N);
    lin_lr_kernel<F1><<<gridLin, TB, 0, stream>>>(h1, w2l, b2l, w2r, b2r, xl, xr, N);
    gat_kernel<2, 32><<<gridWave, TB, 0, stream>>>(xl, xr, row_ptr, ssrc, sea,
                                                   w2e, att2, bias2, h2, N);
    heads_kernel<<<gridWave, TB, 0, stream>>>(h2, wa, ba, wc, bc, ls, (float*)d_out, N);
}

// Round 3
// 534.276 us; speedup vs baseline: 1.8641x; 1.4207x over previous
//
#include <hip/hip_runtime.h>
#include <math.h>

#define DIN   32
#define F1    64   // H1*C1
#define F2    64   // H2*C2

// ---------------- CSR build (rank trick: count atomic also yields placement) ---

__global__ void count_rank_kernel(const int* __restrict__ dstr, int* __restrict__ cnt,
                                  int* __restrict__ rank, int E) {
    int e = blockIdx.x * blockDim.x + threadIdx.x;
    if (e >= E) return;
    int d = dstr[e];
    rank[e] = atomicAdd(&cnt[d], 1);   // rank write is coalesced (indexed by e)
}

__global__ void scan_blocks(const int* __restrict__ cnt, int* __restrict__ partial,
                            int* __restrict__ btot, int n) {
    __shared__ int sh[256];
    int t = threadIdx.x;
    int i = blockIdx.x * 256 + t;
    int v = (i < n) ? cnt[i] : 0;
    sh[t] = v; __syncthreads();
    for (int off = 1; off < 256; off <<= 1) {
        int x = (t >= off) ? sh[t - off] : 0;
        __syncthreads();
        sh[t] += x;
        __syncthreads();
    }
    if (i < n) partial[i] = sh[t] - v;
    if (t == 255) btot[blockIdx.x] = sh[t];
}

__global__ void scan_top(int* __restrict__ btot, int nb) {
    __shared__ int sh[256];
    int t = threadIdx.x;
    int v = (t < nb) ? btot[t] : 0;
    sh[t] = v; __syncthreads();
    for (int off = 1; off < 256; off <<= 1) {
        int x = (t >= off) ? sh[t - off] : 0;
        __syncthreads();
        sh[t] += x;
        __syncthreads();
    }
    if (t < nb) btot[t] = sh[t] - v;
}

__global__ void scan_add(const int* __restrict__ partial, const int* __restrict__ boff,
                         int* __restrict__ row_ptr, int n, int E) {
    int i = blockIdx.x * blockDim.x + threadIdx.x;
    if (i > n) return;
    row_ptr[i] = (i == n) ? E : (partial[i] + boff[i >> 8]);
}

__global__ void scatter_kernel(const int* __restrict__ srcr, const int* __restrict__ dstr,
                               const int* __restrict__ rank, const int* __restrict__ row_ptr,
                               const float* __restrict__ ea,
                               int* __restrict__ ssrc, float* __restrict__ sea, int E) {
    int e = blockIdx.x * blockDim.x + threadIdx.x;
    if (e >= E) return;
    int pos = row_ptr[dstr[e]] + rank[e];
    ssrc[pos] = srcr[e];
    ((float2*)sea)[pos] = ((const float2*)ea)[e];
}

// ---------------- dense linear: xl = x@Wl+bl, xr = x@Wr+br -----------------
template <int K>
__global__ void lin_lr_kernel(const float* __restrict__ x,
                              const float* __restrict__ Wl, const float* __restrict__ bl,
                              const float* __restrict__ Wr, const float* __restrict__ br,
                              float* __restrict__ xl, float* __restrict__ xr, int n) {
    __shared__ float Wsh[K][128];
    __shared__ float bsh[128];
    int t = threadIdx.x;
    for (int idx = t; idx < K * 128; idx += 256) {
        int k = idx >> 7, j = idx & 127;
        Wsh[k][j] = (j < 64) ? Wl[k * 64 + j] : Wr[k * 64 + (j - 64)];
    }
    if (t < 128) bsh[t] = (t < 64) ? bl[t] : br[t - 64];
    __syncthreads();
    int nl = t >> 7;
    int j  = t & 127;
    int node = blockIdx.x * 2 + nl;
    if (node >= n) return;
    const float* xrow = x + node * K;
    float acc = bsh[j];
#pragma unroll
    for (int k = 0; k < K; k++) acc += xrow[k] * Wsh[k][j];
    if (j < 64) xl[node * 64 + j] = acc;
    else        xr[node * 64 + (j - 64)] = acc;
}

// ---------------- GATv2 edge phase -----------------------------------------
// One wave per dst node; 4 edges per iteration; lane = (edge-slot g, feat-quad q).
// Online softmax per edge-slot group, merged at the end; self-loop (attr = mean
// of incoming, accumulated inline) folded last. Sentinel max = -1e30 makes any
// garbage accumulated before the first valid logit self-flush (×exp(-1e30-l)=0).
template <int H, int C>
__global__ void gat_kernel(const float* __restrict__ xl, const float* __restrict__ xr,
                           const int* __restrict__ row_ptr, const int* __restrict__ ssrc,
                           const float* __restrict__ sea,
                           const float* __restrict__ We, const float* __restrict__ att,
                           const float* __restrict__ bias, float* __restrict__ out, int n) {
    constexpr int LPH = C / 4;              // lanes per head within a 16-lane group
    const int lane = threadIdx.x & 63;
    const int wid = (blockIdx.x * blockDim.x + threadIdx.x) >> 6;
    if (wid >= n) return;
    const int i = wid;
    const int g = lane >> 4;                // edge slot 0..3
    const int q = lane & 15;                // feature quad: feats 4q..4q+3

    const float4 xri = ((const float4*)(xr + (size_t)i * 64))[q];
    const float4 we0 = ((const float4*)We)[q];
    const float4 we1 = ((const float4*)(We + 64))[q];
    const float4 av  = ((const float4*)att)[q];

    float mx = -1e30f, den = 0.f;
    float a0 = 0.f, a1 = 0.f, a2 = 0.f, a3 = 0.f;
    float s0 = 0.f, s1 = 0.f;               // running edge-attr sums (per group)

    const int e0 = row_ptr[i], e1 = row_ptr[i + 1];
    for (int eb = e0; eb < e1; eb += 4) {
        int e = eb + g;
        bool valid = (e < e1);
        int ec = valid ? e : e0;            // clamp ADDRESS into valid range
        int s = ssrc[ec];
        float2 eav = ((const float2*)sea)[ec];
        if (!valid) { eav.x = 0.f; eav.y = 0.f; }
        s0 += eav.x; s1 += eav.y;
        float4 xv = ((const float4*)(xl + (size_t)s * 64))[q];
        float z0 = xv.x + xri.x + eav.x * we0.x + eav.y * we1.x;
        float z1 = xv.y + xri.y + eav.x * we0.y + eav.y * we1.y;
        float z2 = xv.z + xri.z + eav.x * we0.z + eav.y * we1.z;
        float z3 = xv.w + xri.w + eav.x * we0.w + eav.y * we1.w;
        z0 = (z0 > 0.f) ? z0 : 0.2f * z0;
        z1 = (z1 > 0.f) ? z1 : 0.2f * z1;
        z2 = (z2 > 0.f) ? z2 : 0.2f * z2;
        z3 = (z3 > 0.f) ? z3 : 0.2f * z3;
        float l = z0 * av.x + z1 * av.y + z2 * av.z + z3 * av.w;
#pragma unroll
        for (int m = 1; m < LPH; m <<= 1) l += __shfl_xor(l, m, 64);
        if (!valid) l = -1e30f;
        float nm = fmaxf(mx, l);
        float sc = __expf(mx - nm);
        float p  = __expf(l - nm);
        den = den * sc + p;
        a0 = a0 * sc + p * xv.x;
        a1 = a1 * sc + p * xv.y;
        a2 = a2 * sc + p * xv.z;
        a3 = a3 * sc + p * xv.w;
        mx = nm;
    }

    // merge the 4 edge-slot groups (and finish the attr sums)
#pragma unroll
    for (int m = 16; m < 64; m <<= 1) {
        float omx  = __shfl_xor(mx, m, 64);
        float oden = __shfl_xor(den, m, 64);
        float o0 = __shfl_xor(a0, m, 64);
        float o1 = __shfl_xor(a1, m, 64);
        float o2 = __shfl_xor(a2, m, 64);
        float o3 = __shfl_xor(a3, m, 64);
        s0 += __shfl_xor(s0, m, 64);
        s1 += __shfl_xor(s1, m, 64);
        float nm = fmaxf(mx, omx);
        float sa = __expf(mx - nm);
        float sb = __expf(omx - nm);
        den = den * sa + oden * sb;
        a0 = a0 * sa + o0 * sb;
        a1 = a1 * sa + o1 * sb;
        a2 = a2 * sa + o2 * sb;
        a3 = a3 * sa + o3 * sb;
        mx = nm;
    }

    // self-loop, attr = mean of incoming (always finite -> flushes any sentinel garbage)
    float degc = fmaxf((float)(e1 - e0), 1.0f);
    float la0 = s0 / degc, la1 = s1 / degc;
    const float4 xlv = ((const float4*)(xl + (size_t)i * 64))[q];
    {
        float z0 = xlv.x + xri.x + la0 * we0.x + la1 * we1.x;
        float z1 = xlv.y + xri.y + la0 * we0.y + la1 * we1.y;
        float z2 = xlv.z + xri.z + la0 * we0.z + la1 * we1.z;
        float z3 = xlv.w + xri.w + la0 * we0.w + la1 * we1.w;
        z0 = (z0 > 0.f) ? z0 : 0.2f * z0;
        z1 = (z1 > 0.f) ? z1 : 0.2f * z1;
        z2 = (z2 > 0.f) ? z2 : 0.2f * z2;
        z3 = (z3 > 0.f) ? z3 : 0.2f * z3;
        float l = z0 * av.x + z1 * av.y + z2 * av.z + z3 * av.w;
#pragma unroll
        for (int m = 1; m < LPH; m <<= 1) l += __shfl_xor(l, m, 64);
        float nm = fmaxf(mx, l);
        float sc = __expf(mx - nm);
        float p  = __expf(l - nm);
        den = den * sc + p;
        a0 = a0 * sc + p * xlv.x;
        a1 = a1 * sc + p * xlv.y;
        a2 = a2 * sc + p * xlv.z;
        a3 = a3 * sc + p * xlv.w;
    }

    if (g == 0) {
        float rd = 1.0f / den;
        const float4 bv = ((const float4*)bias)[q];
        float4 o;
        o.x = fmaxf(a0 * rd + bv.x, 0.f);
        o.y = fmaxf(a1 * rd + bv.y, 0.f);
        o.z = fmaxf(a2 * rd + bv.z, 0.f);
        o.w = fmaxf(a3 * rd + bv.w, 0.f);
        ((float4*)(out + (size_t)i * 64))[q] = o;
    }
}

// ---------------- heads: actor(tanh) + critic + std ------------------------
__global__ void heads_kernel(const float* __restrict__ h, const float* __restrict__ wa,
                             const float* __restrict__ ba, const float* __restrict__ wc,
                             const float* __restrict__ bc, const float* __restrict__ ls,
                             float* __restrict__ out, int n) {
    if (blockIdx.x == 0 && threadIdx.x < 2)
        out[(size_t)n * 2 + threadIdx.x] = expf(ls[threadIdx.x]);
    int lane = threadIdx.x & 63;
    int wid = (blockIdx.x * blockDim.x + threadIdx.x) >> 6;
    if (wid >= n) return;
    float hv = h[wid * 64 + lane];
    float d0 = hv * wa[lane * 2 + 0];
    float d1 = hv * wa[lane * 2 + 1];
    float d2 = hv * wc[lane];
#pragma unroll
    for (int m = 1; m < 64; m <<= 1) {
        d0 += __shfl_xor(d0, m, 64);
        d1 += __shfl_xor(d1, m, 64);
        d2 += __shfl_xor(d2, m, 64);
    }
    if (lane == 0) {
        out[wid * 2 + 0] = tanhf(d0 + ba[0]);
        out[wid * 2 + 1] = tanhf(d1 + ba[1]);
        out[(size_t)n * 2 + 2 + wid] = d2 + bc[0];
    }
}

// ---------------- launch ---------------------------------------------------

extern "C" void kernel_launch(void* const* d_in, const int* in_sizes, int n_in,
                              void* d_out, int out_size, void* d_ws, size_t ws_size,
                              hipStream_t stream) {
    const float* x    = (const float*)d_in[0];
    const int*   ei   = (const int*)  d_in[1];
    const float* ea   = (const float*)d_in[2];
    const float* w1l  = (const float*)d_in[3];
    const float* b1l  = (const float*)d_in[4];
    const float* w1r  = (const float*)d_in[5];
    const float* b1r  = (const float*)d_in[6];
    const float* w1e  = (const float*)d_in[7];
    const float* att1 = (const float*)d_in[8];
    const float* bias1= (const float*)d_in[9];
    const float* w2l  = (const float*)d_in[10];
    const float* b2l  = (const float*)d_in[11];
    const float* w2r  = (const float*)d_in[12];
    const float* b2r  = (const float*)d_in[13];
    const float* w2e  = (const float*)d_in[14];
    const float* att2 = (const float*)d_in[15];
    const float* bias2= (const float*)d_in[16];
    const float* wa   = (const float*)d_in[17];
    const float* ba   = (const float*)d_in[18];
    const float* wc   = (const float*)d_in[19];
    const float* bc   = (const float*)d_in[20];
    const float* ls   = (const float*)d_in[21];

    const int N = in_sizes[0] / DIN;
    const int E = in_sizes[2] / 2;
    const int* srcr = ei;
    const int* dstr = ei + E;

    char* p = (char*)d_ws;
    auto alloc = [&](size_t bytes) -> void* {
        void* r = (void*)p;
        p += (bytes + 255) & ~(size_t)255;
        return r;
    };
    int*   cnt     = (int*)  alloc((size_t)N * 4);
    int*   rank    = (int*)  alloc((size_t)E * 4);
    int*   partial = (int*)  alloc((size_t)N * 4);
    int*   btot    = (int*)  alloc(256 * 4);
    int*   row_ptr = (int*)  alloc((size_t)(N + 1) * 4);
    int*   ssrc    = (int*)  alloc((size_t)E * 4);
    float* sea     = (float*)alloc((size_t)E * 8);
    float* xl      = (float*)alloc((size_t)N * F1 * 4);
    float* xr      = (float*)alloc((size_t)N * F1 * 4);
    float* h1      = (float*)alloc((size_t)N * F1 * 4);
    float* h2      = (float*)alloc((size_t)N * F2 * 4);
    (void)ws_size; (void)n_in; (void)out_size;

    hipMemsetAsync(cnt, 0, (size_t)N * 4, stream);

    const int TB = 256;
    int gridE  = (E + TB - 1) / TB;
    int nbScan = (N + TB - 1) / TB;          // <= 256 required (196 for N=50000)
    int gridN1 = (N + 1 + TB - 1) / TB;
    int gridLin = (N + 1) / 2;
    int gridWave = (N + 3) / 4;

    count_rank_kernel<<<gridE, TB, 0, stream>>>(dstr, cnt, rank, E);
    scan_blocks<<<nbScan, TB, 0, stream>>>(cnt, partial, btot, N);
    scan_top<<<1, TB, 0, stream>>>(btot, nbScan);
    scan_add<<<gridN1, TB, 0, stream>>>(partial, btot, row_ptr, N, E);
    scatter_kernel<<<gridE, TB, 0, stream>>>(srcr, dstr, rank, row_ptr, ea, ssrc, sea, E);

    lin_lr_kernel<DIN><<<gridLin, TB, 0, stream>>>(x, w1l, b1l, w1r, b1r, xl, xr, N);
    gat_kernel<4, 16><<<gridWave, TB, 0, stream>>>(xl, xr, row_ptr, ssrc, sea,
                                                   w1e, att1, bias1, h1, N);
    lin_lr_kernel<F1><<<gridLin, TB, 0, stream>>>(h1, w2l, b2l, w2r, b2r, xl, xr, N);
    gat_kernel<2, 32><<<gridWave, TB, 0, stream>>>(xl, xr, row_ptr, ssrc, sea,
                                                   w2e, att2, bias2, h2, N);
    heads_kernel<<<gridWave, TB, 0, stream>>>(h2, wa, ba, wc, bc, ls, (float*)d_out, N);
}